// Round 1
// baseline (72499.078 us; speedup 1.0000x reference)
//
#include <hip/hip_runtime.h>
#include <math.h>

#define S 2048
#define MARGIN 0.7f
#define ITERS 500
#define NBLK 256   // cooperative grid: 1 block/CU on 256 CUs
#define TPB 512    // 8 waves/block, wave-per-row, 8 rows/block

// ---------------------------------------------------------------------------
// init: log-marginals, zero accumulators, zero barrier/change flags
// ---------------------------------------------------------------------------
__global__ __launch_bounds__(256) void init_marg_k(const float* __restrict__ qa,
                                                   const float* __restrict__ ta,
                                                   float* __restrict__ lmu,
                                                   float* __restrict__ lnu,
                                                   float* __restrict__ vt,
                                                   float* __restrict__ dist2,
                                                   unsigned* __restrict__ chg,
                                                   unsigned* __restrict__ bar) {
  int i = blockIdx.x * 256 + threadIdx.x;
  lmu[i] = __logf(qa[i]);
  lnu[i] = __logf(ta[i]);
  vt[i] = 0.f;     // will accumulate y2 (vt init = v0 + y2 = y2 since v0 = 0)
  dist2[i] = 0.f;
  if (i < 512) chg[i] = 0u;   // per-iteration change flags (500 used)
  if (i == 0) *bar = 0u;      // grid barrier counter (must reset every graph replay)
}

// vt[j] += sum_d TF[d,j]^2   (8 j-blocks x 8 d-chunks, atomic combine)
__global__ __launch_bounds__(256) void colsumsq_k(const float* __restrict__ TF,
                                                  float* __restrict__ vt) {
  int jb = blockIdx.x & 7, dc = blockIdx.x >> 3;
  int j = jb * 256 + threadIdx.x;
  int d0 = dc * 256;
  float acc = 0.f;
  for (int d = d0; d < d0 + 256; ++d) {
    float v = TF[d * S + j];
    acc = fmaf(v, v, acc);
  }
  atomicAdd(&vt[j], acc);
}

// ---------------------------------------------------------------------------
// C[i,j] = alpha * sum_k A[k*S+i] * B[k*S+j]   (128x128 tile, BK=16, 8x8/thread)
// ---------------------------------------------------------------------------
__global__ __launch_bounds__(256) void gemm_tn_k(const float* __restrict__ A,
                                                 const float* __restrict__ B,
                                                 float* __restrict__ C, float alpha) {
  __shared__ float As[16][128];
  __shared__ float Bs[16][128];
  int t = threadIdx.x;
  int i0 = blockIdx.y * 128, j0 = blockIdx.x * 128;
  int tx = t & 15, ty = t >> 4;
  float acc[8][8];
#pragma unroll
  for (int r = 0; r < 8; ++r)
#pragma unroll
    for (int c = 0; c < 8; ++c) acc[r][c] = 0.f;

  int e = t * 4;
  int dd0 = e >> 7, ii = e & 127;
  int dd1 = dd0 + 8;
  for (int k0 = 0; k0 < S; k0 += 16) {
    float4 a0 = *(const float4*)&A[(k0 + dd0) * S + i0 + ii];
    float4 b0 = *(const float4*)&B[(k0 + dd0) * S + j0 + ii];
    float4 a1 = *(const float4*)&A[(k0 + dd1) * S + i0 + ii];
    float4 b1 = *(const float4*)&B[(k0 + dd1) * S + j0 + ii];
    __syncthreads();
    *(float4*)&As[dd0][ii] = a0; *(float4*)&Bs[dd0][ii] = b0;
    *(float4*)&As[dd1][ii] = a1; *(float4*)&Bs[dd1][ii] = b1;
    __syncthreads();
#pragma unroll
    for (int kk = 0; kk < 16; ++kk) {
      float a[8], b[8];
      *(float4*)&a[0] = *(const float4*)&As[kk][ty * 8];
      *(float4*)&a[4] = *(const float4*)&As[kk][ty * 8 + 4];
      *(float4*)&b[0] = *(const float4*)&Bs[kk][tx * 4];
      *(float4*)&b[4] = *(const float4*)&Bs[kk][64 + tx * 4];
#pragma unroll
      for (int r = 0; r < 8; ++r)
#pragma unroll
        for (int c = 0; c < 8; ++c) acc[r][c] = fmaf(a[r], b[c], acc[r][c]);
    }
  }
#pragma unroll
  for (int r = 0; r < 8; ++r) {
    int i = i0 + ty * 8 + r;
    float4 o0 = make_float4(acc[r][0] * alpha, acc[r][1] * alpha, acc[r][2] * alpha, acc[r][3] * alpha);
    float4 o1 = make_float4(acc[r][4] * alpha, acc[r][5] * alpha, acc[r][6] * alpha, acc[r][7] * alpha);
    *(float4*)&C[i * S + j0 + tx * 4] = o0;
    *(float4*)&C[i * S + j0 + 64 + tx * 4] = o1;
  }
}

// ---------------------------------------------------------------------------
// out[j*S+i] = in[i*S+j]  (64x64 LDS tiles)
// ---------------------------------------------------------------------------
__global__ __launch_bounds__(256) void transpose_k(const float* __restrict__ in,
                                                   float* __restrict__ out) {
  __shared__ float tile[64][65];
  int i0 = blockIdx.y * 64, j0 = blockIdx.x * 64;
  int tx = threadIdx.x & 63, ty = threadIdx.x >> 6;  // ty 0..3
#pragma unroll
  for (int r = 0; r < 16; ++r) {
    int row = r * 4 + ty;
    tile[row][tx] = in[(i0 + row) * S + j0 + tx];
  }
  __syncthreads();
#pragma unroll
  for (int r = 0; r < 16; ++r) {
    int row = r * 4 + ty;
    out[(j0 + row) * S + i0 + tx] = tile[tx][row];
  }
}

// ---------------------------------------------------------------------------
// Persistent cooperative Sinkhorn.
// 256 blocks x 512 threads. wave-per-row: row = bid*8 + wave, 32 elems/lane.
// Each lane keeps its Gp-row slice (32 f32) and GpT-row slice (32 f32) in
// VGPRs for all 500 iterations -> zero matrix traffic inside the loop.
// Between the two half-iterations: device-wide sense barrier (monotonic
// counter, 1 atomic/block) with explicit __threadfence() release/acquire to
// cover cross-XCD L2 non-coherence for the 8KB potential vectors.
// Bitwise fixed-point early exit: if an entire iteration changes neither u
// nor v bitwise, all further iterations are identities -> break (exact).
// ---------------------------------------------------------------------------
#define PADD(P, A) P.x += A.x; P.y += A.y; P.z += A.z; P.w += A.w
#define PMAX(P) fmaxf(fmaxf(P.x, P.y), fmaxf(P.z, P.w))
#define PEXPS(P) (__expf(P.x - m) + __expf(P.y - m) + __expf(P.z - m) + __expf(P.w - m))

__device__ __forceinline__ void gridbar(unsigned* __restrict__ bar,
                                        unsigned* __restrict__ chgw,
                                        unsigned* s_chg, unsigned target) {
  __threadfence();   // release: drain own stores, flush XCD L2 to coherence point
  __syncthreads();
  if (threadIdx.x == 0) {
    if (*s_chg != 0u) {  // block-coalesced change flag -> one atomic max
      __hip_atomic_fetch_or(chgw, 1u, __ATOMIC_RELAXED, __HIP_MEMORY_SCOPE_AGENT);
      *s_chg = 0u;       // reset here: ordered before trailing __syncthreads
    }
    __hip_atomic_fetch_add(bar, 1u, __ATOMIC_ACQ_REL, __HIP_MEMORY_SCOPE_AGENT);
    while (__hip_atomic_load(bar, __ATOMIC_RELAXED, __HIP_MEMORY_SCOPE_AGENT) < target)
      __builtin_amdgcn_s_sleep(2);
  }
  __syncthreads();
  __threadfence();   // acquire: invalidate stale L1/L2 before reading others' pots
}

__device__ __forceinline__ void lse_row_pass(
    float4 a0, float4 a1, float4 a2, float4 a3,
    float4 a4, float4 a5, float4 a6, float4 a7,
    const float* __restrict__ inPot, float margr,
    float* __restrict__ outPot, int row, int lane, int j0,
    float& prev, unsigned* s_chg) {
  float4 p0 = *(const float4*)&inPot[j0];
  float4 p1 = *(const float4*)&inPot[j0 + 256];
  float4 p2 = *(const float4*)&inPot[j0 + 512];
  float4 p3 = *(const float4*)&inPot[j0 + 768];
  float4 p4 = *(const float4*)&inPot[j0 + 1024];
  float4 p5 = *(const float4*)&inPot[j0 + 1280];
  float4 p6 = *(const float4*)&inPot[j0 + 1536];
  float4 p7 = *(const float4*)&inPot[j0 + 1792];
  PADD(p0, a0); PADD(p1, a1); PADD(p2, a2); PADD(p3, a3);
  PADD(p4, a4); PADD(p5, a5); PADD(p6, a6); PADD(p7, a7);
  float m0 = PMAX(p0), m1 = PMAX(p1), m2 = PMAX(p2), m3 = PMAX(p3);
  float m4 = PMAX(p4), m5 = PMAX(p5), m6 = PMAX(p6), m7 = PMAX(p7);
  m0 = fmaxf(m0, m1); m2 = fmaxf(m2, m3); m4 = fmaxf(m4, m5); m6 = fmaxf(m6, m7);
  float m = fmaxf(fmaxf(m0, m2), fmaxf(m4, m6));
#pragma unroll
  for (int off = 32; off; off >>= 1) m = fmaxf(m, __shfl_xor(m, off));
  // m is now the exact row max (same as previous two-stage kernel)
  float s = PEXPS(p0) + PEXPS(p1) + PEXPS(p2) + PEXPS(p3) +
            PEXPS(p4) + PEXPS(p5) + PEXPS(p6) + PEXPS(p7);
#pragma unroll
  for (int off = 32; off; off >>= 1) s += __shfl_xor(s, off);
  if (lane == 0) {
    float nv = margr - (m + __logf(s));
    if (__float_as_uint(nv) != __float_as_uint(prev)) *s_chg = 1u;
    prev = nv;
    outPot[row] = nv;
  }
}

__global__ __launch_bounds__(TPB) void sinkhorn_k(
    const float* __restrict__ Gp, const float* __restrict__ GpT,
    const float* __restrict__ lmu, const float* __restrict__ lnu,
    float* __restrict__ ut, float* __restrict__ vt,
    unsigned* __restrict__ chg, unsigned* __restrict__ bar) {
  __shared__ unsigned s_chg, s_stop;
  const int t = threadIdx.x;
  const int wv = t >> 6, lane = t & 63;
  const int row = (blockIdx.x << 3) + wv;
  const int j0 = lane << 2;
  const float* gu = Gp + (size_t)row * S;
  const float* gv = GpT + (size_t)row * S;
  // G slices live in VGPRs for the whole loop (~64 regs + pot temps, <128)
  float4 a0 = *(const float4*)&gu[j0];
  float4 a1 = *(const float4*)&gu[j0 + 256];
  float4 a2 = *(const float4*)&gu[j0 + 512];
  float4 a3 = *(const float4*)&gu[j0 + 768];
  float4 a4 = *(const float4*)&gu[j0 + 1024];
  float4 a5 = *(const float4*)&gu[j0 + 1280];
  float4 a6 = *(const float4*)&gu[j0 + 1536];
  float4 a7 = *(const float4*)&gu[j0 + 1792];
  float4 b0 = *(const float4*)&gv[j0];
  float4 b1 = *(const float4*)&gv[j0 + 256];
  float4 b2 = *(const float4*)&gv[j0 + 512];
  float4 b3 = *(const float4*)&gv[j0 + 768];
  float4 b4 = *(const float4*)&gv[j0 + 1024];
  float4 b5 = *(const float4*)&gv[j0 + 1280];
  float4 b6 = *(const float4*)&gv[j0 + 1536];
  float4 b7 = *(const float4*)&gv[j0 + 1792];
  const float lmu_r = lmu[row];
  const float lnu_r = lnu[row];
  float prevU = __uint_as_float(0x7fc00000u);  // NaN -> first compare flags "changed"
  float prevV = prevU;
  if (t == 0) { s_chg = 0u; s_stop = 0u; }
  __syncthreads();
  unsigned phase = 0;

  for (int it = 0; it < ITERS; ++it) {
    // u-pass: ut[row] = lmu - LSE_j(Gp[row,j] + vt[j])
    lse_row_pass(a0, a1, a2, a3, a4, a5, a6, a7, vt, lmu_r, ut, row, lane, j0,
                 prevU, &s_chg);
    gridbar(bar, &chg[it], &s_chg, ++phase * NBLK);
    // v-pass: vt[row] = lnu - LSE_i(GpT[row,i] + ut[i])
    lse_row_pass(b0, b1, b2, b3, b4, b5, b6, b7, ut, lnu_r, vt, row, lane, j0,
                 prevV, &s_chg);
    gridbar(bar, &chg[it], &s_chg, ++phase * NBLK);
    // exact early exit: all writes to chg[it] precede barrier 2it+2, so every
    // block reads the same value -> uniform break, no deadlock.
    if ((it & 7) == 7) {
      if (t == 0)
        s_stop = (__hip_atomic_load(&chg[it], __ATOMIC_RELAXED,
                                    __HIP_MEMORY_SCOPE_AGENT) == 0u) ? 1u : 0u;
      __syncthreads();
      if (s_stop) break;
    }
  }
}

// ---------------------------------------------------------------------------
// RT[d,i] = sum_j TF[d,j] * exp( GpT[j*S+i] + ut[i] + vt[j] )
// ---------------------------------------------------------------------------
__global__ __launch_bounds__(256) void rt_gemm_k(const float* __restrict__ TF,
                                                 const float* __restrict__ GpT,
                                                 const float* __restrict__ ut,
                                                 const float* __restrict__ vt,
                                                 float* __restrict__ RT) {
  __shared__ float As[16][128];
  __shared__ float Bs[16][128];
  int t = threadIdx.x;
  int d0 = blockIdx.y * 128, i0 = blockIdx.x * 128;
  int tx = t & 15, ty = t >> 4;
  float acc[8][8];
#pragma unroll
  for (int r = 0; r < 8; ++r)
#pragma unroll
    for (int c = 0; c < 8; ++c) acc[r][c] = 0.f;

  int akk = (t * 4) & 15, add0 = t >> 2;
  int eb = t * 4;
  int bkk0 = eb >> 7, bii = eb & 127, bkk1 = bkk0 + 8;
  float4 u4 = *(const float4*)&ut[i0 + bii];

  for (int k0 = 0; k0 < S; k0 += 16) {
    float4 av0 = *(const float4*)&TF[(d0 + add0) * S + k0 + akk];
    float4 av1 = *(const float4*)&TF[(d0 + add0 + 64) * S + k0 + akk];
    float4 g0 = *(const float4*)&GpT[(k0 + bkk0) * S + i0 + bii];
    float4 g1 = *(const float4*)&GpT[(k0 + bkk1) * S + i0 + bii];
    float v0 = vt[k0 + bkk0], v1 = vt[k0 + bkk1];
    __syncthreads();
    As[akk + 0][add0] = av0.x; As[akk + 1][add0] = av0.y;
    As[akk + 2][add0] = av0.z; As[akk + 3][add0] = av0.w;
    As[akk + 0][add0 + 64] = av1.x; As[akk + 1][add0 + 64] = av1.y;
    As[akk + 2][add0 + 64] = av1.z; As[akk + 3][add0 + 64] = av1.w;
    float4 p0 = make_float4(__expf(g0.x + u4.x + v0), __expf(g0.y + u4.y + v0),
                            __expf(g0.z + u4.z + v0), __expf(g0.w + u4.w + v0));
    float4 p1 = make_float4(__expf(g1.x + u4.x + v1), __expf(g1.y + u4.y + v1),
                            __expf(g1.z + u4.z + v1), __expf(g1.w + u4.w + v1));
    *(float4*)&Bs[bkk0][bii] = p0;
    *(float4*)&Bs[bkk1][bii] = p1;
    __syncthreads();
#pragma unroll
    for (int kk = 0; kk < 16; ++kk) {
      float a[8], b[8];
      *(float4*)&a[0] = *(const float4*)&As[kk][ty * 8];
      *(float4*)&a[4] = *(const float4*)&As[kk][ty * 8 + 4];
      *(float4*)&b[0] = *(const float4*)&Bs[kk][tx * 4];
      *(float4*)&b[4] = *(const float4*)&Bs[kk][64 + tx * 4];
#pragma unroll
      for (int r = 0; r < 8; ++r)
#pragma unroll
        for (int c = 0; c < 8; ++c) acc[r][c] = fmaf(a[r], b[c], acc[r][c]);
    }
  }
#pragma unroll
  for (int r = 0; r < 8; ++r) {
    int d = d0 + ty * 8 + r;
    *(float4*)&RT[d * S + i0 + tx * 4] = *(float4*)&acc[r][0];
    *(float4*)&RT[d * S + i0 + 64 + tx * 4] = *(float4*)&acc[r][4];
  }
}

// dist2[i] += sum_{d in chunk} (qa[i]*QF[d,i] - RT[d,i])^2
__global__ __launch_bounds__(256) void dist2_partial_k(const float* __restrict__ QF,
                                                       const float* __restrict__ RT,
                                                       const float* __restrict__ qa,
                                                       float* __restrict__ dist2) {
  int ib = blockIdx.x & 7, dc = blockIdx.x >> 3;
  int i = ib * 256 + threadIdx.x;
  float qai = qa[i];
  float acc = 0.f;
  int d0 = dc * 256;
  for (int d = d0; d < d0 + 256; ++d) {
    float q = QF[d * S + i];
    float r = RT[d * S + i];
    float x = fmaf(qai, q, -r);
    acc = fmaf(x, x, acc);
  }
  atomicAdd(&dist2[i], acc);
}

__global__ __launch_bounds__(256) void loss_final_k(const float* __restrict__ dist2,
                                                    const float* __restrict__ label,
                                                    float* __restrict__ out) {
  int t = threadIdx.x;
  float acc = 0.f;
#pragma unroll
  for (int k = 0; k < 8; ++k) {
    int i = t + k * 256;
    float d2 = dist2[i];
    float dist = sqrtf(d2);
    float lab = label[i];
    float neg = fmaxf(MARGIN - dist, 0.f);
    acc += 0.5f * lab * d2 + 0.5f * (1.f - lab) * neg * neg;
  }
#pragma unroll
  for (int off = 32; off; off >>= 1) acc += __shfl_xor(acc, off);
  __shared__ float wsum[4];
  int wave = t >> 6, lane = t & 63;
  if (lane == 0) wsum[wave] = acc;
  __syncthreads();
  if (t == 0) out[0] = wsum[0] + wsum[1] + wsum[2] + wsum[3];
}

// ---------------------------------------------------------------------------
extern "C" void kernel_launch(void* const* d_in, const int* in_sizes, int n_in,
                              void* d_out, int out_size, void* d_ws, size_t ws_size,
                              hipStream_t stream) {
  const float* QF  = (const float*)d_in[0];  // [D, m] d-major
  const float* qa  = (const float*)d_in[1];  // [m]
  const float* TF  = (const float*)d_in[2];  // [D, n] d-major
  const float* ta  = (const float*)d_in[3];  // [n]
  const float* lab = (const float*)d_in[4];  // [m]
  float* out = (float*)d_out;

  float* ws = (float*)d_ws;
  float* Gp    = ws;                  // S*S : G' = -2 X^T Y  (reused as RT later)
  float* GpT   = Gp + S * S;          // S*S : G'^T
  float* ut    = GpT + S * S;         // S
  float* vt    = ut + S;              // S
  float* lmu   = vt + S;              // S
  float* lnu   = lmu + S;             // S
  float* dist2 = lnu + S;             // S
  unsigned* chg = (unsigned*)(dist2 + S);  // 512 u32 (500 used)
  unsigned* bar = chg + 512;               // 1 u32
  // total: 2*S*S + 5*S floats + 513 u32 ~= 33.6 MB

  init_marg_k<<<8, 256, 0, stream>>>(qa, ta, lmu, lnu, vt, dist2, chg, bar);
  colsumsq_k<<<64, 256, 0, stream>>>(TF, vt);  // vt = y2 (== v0 + y2)
  gemm_tn_k<<<dim3(16, 16), 256, 0, stream>>>(QF, TF, Gp, -2.0f);
  transpose_k<<<dim3(32, 32), 256, 0, stream>>>(Gp, GpT);

  // whole Sinkhorn loop in one persistent cooperative kernel
  {
    const float* cGp = Gp; const float* cGpT = GpT;
    const float* clmu = lmu; const float* clnu = lnu;
    float* cut = ut; float* cvt = vt;
    unsigned* cchg = chg; unsigned* cbar = bar;
    void* kargs[] = {&cGp, &cGpT, &clmu, &clnu, &cut, &cvt, &cchg, &cbar};
    hipLaunchCooperativeKernel((const void*)sinkhorn_k, dim3(NBLK), dim3(TPB),
                               kargs, 0, stream);
  }

  // RT = P @ tf computed transposed: RT[d,i]; aliases Gp (G' dead after loop)
  rt_gemm_k<<<dim3(16, 16), 256, 0, stream>>>(TF, GpT, ut, vt, Gp);
  dist2_partial_k<<<64, 256, 0, stream>>>(QF, Gp, qa, dist2);
  loss_final_k<<<1, 256, 0, stream>>>(dist2, lab, out);
}

// Round 3
// 5240.894 us; speedup vs baseline: 13.8333x; 13.8333x over previous
//
#include <hip/hip_runtime.h>
#include <math.h>

#define S 2048
#define MARGIN 0.7f
#define ITERS 500
#define NBLK 256    // cooperative grid: 1 block/CU on 256 CUs
#define TPB 512     // 8 waves/block, wave-per-row, 8 rows/block
#define NGRP 16     // two-level barrier: 16 groups x 16 blocks

// ---------------------------------------------------------------------------
// init: log-marginals, zero accumulators, zero barrier counters
// ---------------------------------------------------------------------------
__global__ __launch_bounds__(256) void init_marg_k(const float* __restrict__ qa,
                                                   const float* __restrict__ ta,
                                                   float* __restrict__ lmu,
                                                   float* __restrict__ lnu,
                                                   float* __restrict__ vt,
                                                   float* __restrict__ dist2,
                                                   unsigned* __restrict__ grp,
                                                   unsigned* __restrict__ gbar) {
  int i = blockIdx.x * 256 + threadIdx.x;
  lmu[i] = __logf(qa[i]);
  lnu[i] = __logf(ta[i]);
  vt[i] = 0.f;     // will accumulate y2 (vt init = v0 + y2 = y2 since v0 = 0)
  dist2[i] = 0.f;
  if (i < 512) grp[i] = 0u;    // group arrival counters (stride-32 slots)
  if (i == 0) *gbar = 0u;      // global phase counter (reset every graph replay)
}

// vt[j] += sum_d TF[d,j]^2   (8 j-blocks x 8 d-chunks, atomic combine)
__global__ __launch_bounds__(256) void colsumsq_k(const float* __restrict__ TF,
                                                  float* __restrict__ vt) {
  int jb = blockIdx.x & 7, dc = blockIdx.x >> 3;
  int j = jb * 256 + threadIdx.x;
  int d0 = dc * 256;
  float acc = 0.f;
  for (int d = d0; d < d0 + 256; ++d) {
    float v = TF[d * S + j];
    acc = fmaf(v, v, acc);
  }
  atomicAdd(&vt[j], acc);
}

// ---------------------------------------------------------------------------
// C[i,j] = alpha * sum_k A[k*S+i] * B[k*S+j]   (128x128 tile, BK=16, 8x8/thread)
// ---------------------------------------------------------------------------
__global__ __launch_bounds__(256) void gemm_tn_k(const float* __restrict__ A,
                                                 const float* __restrict__ B,
                                                 float* __restrict__ C, float alpha) {
  __shared__ float As[16][128];
  __shared__ float Bs[16][128];
  int t = threadIdx.x;
  int i0 = blockIdx.y * 128, j0 = blockIdx.x * 128;
  int tx = t & 15, ty = t >> 4;
  float acc[8][8];
#pragma unroll
  for (int r = 0; r < 8; ++r)
#pragma unroll
    for (int c = 0; c < 8; ++c) acc[r][c] = 0.f;

  int e = t * 4;
  int dd0 = e >> 7, ii = e & 127;
  int dd1 = dd0 + 8;
  for (int k0 = 0; k0 < S; k0 += 16) {
    float4 a0 = *(const float4*)&A[(k0 + dd0) * S + i0 + ii];
    float4 b0 = *(const float4*)&B[(k0 + dd0) * S + j0 + ii];
    float4 a1 = *(const float4*)&A[(k0 + dd1) * S + i0 + ii];
    float4 b1 = *(const float4*)&B[(k0 + dd1) * S + j0 + ii];
    __syncthreads();
    *(float4*)&As[dd0][ii] = a0; *(float4*)&Bs[dd0][ii] = b0;
    *(float4*)&As[dd1][ii] = a1; *(float4*)&Bs[dd1][ii] = b1;
    __syncthreads();
#pragma unroll
    for (int kk = 0; kk < 16; ++kk) {
      float a[8], b[8];
      *(float4*)&a[0] = *(const float4*)&As[kk][ty * 8];
      *(float4*)&a[4] = *(const float4*)&As[kk][ty * 8 + 4];
      *(float4*)&b[0] = *(const float4*)&Bs[kk][tx * 4];
      *(float4*)&b[4] = *(const float4*)&Bs[kk][64 + tx * 4];
#pragma unroll
      for (int r = 0; r < 8; ++r)
#pragma unroll
        for (int c = 0; c < 8; ++c) acc[r][c] = fmaf(a[r], b[c], acc[r][c]);
    }
  }
#pragma unroll
  for (int r = 0; r < 8; ++r) {
    int i = i0 + ty * 8 + r;
    float4 o0 = make_float4(acc[r][0] * alpha, acc[r][1] * alpha, acc[r][2] * alpha, acc[r][3] * alpha);
    float4 o1 = make_float4(acc[r][4] * alpha, acc[r][5] * alpha, acc[r][6] * alpha, acc[r][7] * alpha);
    *(float4*)&C[i * S + j0 + tx * 4] = o0;
    *(float4*)&C[i * S + j0 + 64 + tx * 4] = o1;
  }
}

// ---------------------------------------------------------------------------
// out[j*S+i] = in[i*S+j]  (64x64 LDS tiles)
// ---------------------------------------------------------------------------
__global__ __launch_bounds__(256) void transpose_k(const float* __restrict__ in,
                                                   float* __restrict__ out) {
  __shared__ float tile[64][65];
  int i0 = blockIdx.y * 64, j0 = blockIdx.x * 64;
  int tx = threadIdx.x & 63, ty = threadIdx.x >> 6;  // ty 0..3
#pragma unroll
  for (int r = 0; r < 16; ++r) {
    int row = r * 4 + ty;
    tile[row][tx] = in[(i0 + row) * S + j0 + tx];
  }
  __syncthreads();
#pragma unroll
  for (int r = 0; r < 16; ++r) {
    int row = r * 4 + ty;
    out[(j0 + row) * S + i0 + tx] = tile[tx][row];
  }
}

// ---------------------------------------------------------------------------
// Persistent cooperative Sinkhorn, STATIC 136KB LDS-resident G, fence-free.
//
// 256 blocks x 512 threads, 1 block/CU (forced by static LDS). Each block
// stages its 8 Gp rows + 8 GpT rows into LDS once; the 500-iteration loop
// touches only LDS + the 8KB potential vectors. Cross-XCD coherence for the
// potentials: fine-grained agent-scope relaxed atomics (sc-flagged, bypass
// the non-coherent L1/L2). NO __threadfence anywhere (round-1's per-wave
// buffer_wbl2/buffer_inv was the 142us/iter stall). Ordering: the compiler
// drains vmcnt(0) before every s_barrier, so each wave's pot store completes
// before thread 0 arrives at the grid barrier.
// Two-level barrier: 16 groups x 16 blocks, counters on spread cache lines.
// No early exit (round 1 showed it never fires; removes the only possible
// cross-block divergence).
// ---------------------------------------------------------------------------
#define PADD(P, A) P.x += A.x; P.y += A.y; P.z += A.z; P.w += A.w
#define PMAX(P) fmaxf(fmaxf(P.x, P.y), fmaxf(P.z, P.w))
#define PEXPS(P) (__expf(P.x - m) + __expf(P.y - m) + __expf(P.z - m) + __expf(P.w - m))

__device__ __forceinline__ void stage_pot(const float* __restrict__ src,
                                          float* __restrict__ s_pot, int t) {
  const unsigned long long* s64 = (const unsigned long long*)src;
  unsigned long long* d64 = (unsigned long long*)s_pot;
#pragma unroll
  for (int k = 0; k < 2; ++k) {
    int idx = t + (k << 9);
    d64[idx] = __hip_atomic_load(&s64[idx], __ATOMIC_RELAXED,
                                 __HIP_MEMORY_SCOPE_AGENT);
  }
}

// wave-uniform LSE over 2048 entries of (grow[j] + s_pot[j]); exact row max
__device__ __forceinline__ float lse_row(const float* __restrict__ grow,
                                         const float* __restrict__ s_pot,
                                         int lane) {
  int j0 = lane << 2;
  float4 p0 = *(const float4*)&s_pot[j0];
  float4 p1 = *(const float4*)&s_pot[j0 + 256];
  float4 p2 = *(const float4*)&s_pot[j0 + 512];
  float4 p3 = *(const float4*)&s_pot[j0 + 768];
  float4 p4 = *(const float4*)&s_pot[j0 + 1024];
  float4 p5 = *(const float4*)&s_pot[j0 + 1280];
  float4 p6 = *(const float4*)&s_pot[j0 + 1536];
  float4 p7 = *(const float4*)&s_pot[j0 + 1792];
  float4 a0 = *(const float4*)&grow[j0];
  float4 a1 = *(const float4*)&grow[j0 + 256];
  float4 a2 = *(const float4*)&grow[j0 + 512];
  float4 a3 = *(const float4*)&grow[j0 + 768];
  float4 a4 = *(const float4*)&grow[j0 + 1024];
  float4 a5 = *(const float4*)&grow[j0 + 1280];
  float4 a6 = *(const float4*)&grow[j0 + 1536];
  float4 a7 = *(const float4*)&grow[j0 + 1792];
  PADD(p0, a0); PADD(p1, a1); PADD(p2, a2); PADD(p3, a3);
  PADD(p4, a4); PADD(p5, a5); PADD(p6, a6); PADD(p7, a7);
  float m0 = PMAX(p0), m1 = PMAX(p1), m2 = PMAX(p2), m3 = PMAX(p3);
  float m4 = PMAX(p4), m5 = PMAX(p5), m6 = PMAX(p6), m7 = PMAX(p7);
  m0 = fmaxf(m0, m1); m2 = fmaxf(m2, m3); m4 = fmaxf(m4, m5); m6 = fmaxf(m6, m7);
  float m = fmaxf(fmaxf(m0, m2), fmaxf(m4, m6));
#pragma unroll
  for (int off = 32; off; off >>= 1) m = fmaxf(m, __shfl_xor(m, off));
  float s = PEXPS(p0) + PEXPS(p1) + PEXPS(p2) + PEXPS(p3) +
            PEXPS(p4) + PEXPS(p5) + PEXPS(p6) + PEXPS(p7);
#pragma unroll
  for (int off = 32; off; off >>= 1) s += __shfl_xor(s, off);
  return m + __logf(s);
}

__device__ __forceinline__ void gridbar(unsigned* __restrict__ grp,
                                        unsigned* __restrict__ gbar,
                                        int g, unsigned ph) {
  // entering waves have drained their pot stores: compiler emits
  // s_waitcnt vmcnt(0) before s_barrier for __syncthreads
  __syncthreads();
  if (threadIdx.x == 0) {
    unsigned old = __hip_atomic_fetch_add(&grp[g * 32], 1u, __ATOMIC_RELAXED,
                                          __HIP_MEMORY_SCOPE_AGENT);
    if ((old & (NGRP - 1)) == NGRP - 1)  // 16th arrival of this group, this phase
      __hip_atomic_fetch_add(gbar, 1u, __ATOMIC_RELAXED, __HIP_MEMORY_SCOPE_AGENT);
    unsigned tgt = (ph + 1u) * NGRP;
    while (__hip_atomic_load(gbar, __ATOMIC_RELAXED, __HIP_MEMORY_SCOPE_AGENT) < tgt)
      __builtin_amdgcn_s_sleep(1);
  }
  __syncthreads();
}

__global__ __launch_bounds__(TPB) void sinkhorn_k(
    const float* __restrict__ Gp, const float* __restrict__ GpT,
    const float* __restrict__ lmu, const float* __restrict__ lnu,
    float* __restrict__ ut, float* __restrict__ vt,
    unsigned* __restrict__ grp, unsigned* __restrict__ gbar) {
  __shared__ float s_gu[8 * S];    // 64KB: this block's 8 Gp rows
  __shared__ float s_gv[8 * S];    // 64KB: this block's 8 GpT rows
  __shared__ float s_pot[S];       // 8KB : staged potential vector

  const int t = threadIdx.x;
  const int wv = t >> 6, lane = t & 63;
  const int bid = blockIdx.x;
  const int row = (bid << 3) + wv;
  const int g = bid & (NGRP - 1);

  // one-time stage of this block's G rows into LDS
  {
    const float* gu = Gp + (size_t)row * S;
    const float* gv = GpT + (size_t)row * S;
    float* lgu = s_gu + wv * S;
    float* lgv = s_gv + wv * S;
#pragma unroll
    for (int c = 0; c < 8; ++c) {
      int j = (lane << 2) + (c << 8);
      *(float4*)&lgu[j] = *(const float4*)&gu[j];
      *(float4*)&lgv[j] = *(const float4*)&gv[j];
    }
  }
  const float lmu_r = lmu[row];
  const float lnu_r = lnu[row];
  const float* grow_u = s_gu + wv * S;
  const float* grow_v = s_gv + wv * S;
  unsigned ph = 0;
  __syncthreads();

  for (int it = 0; it < ITERS; ++it) {
    // ---- u-pass: ut[row] = lmu - LSE_j(Gp[row,j] + vt[j]) ----
    stage_pot(vt, s_pot, t);
    __syncthreads();
    {
      float nv = lmu_r - lse_row(grow_u, s_pot, lane);
      if (lane == 0)
        __hip_atomic_store(&ut[row], nv, __ATOMIC_RELAXED,
                           __HIP_MEMORY_SCOPE_AGENT);
    }
    gridbar(grp, gbar, g, ph); ++ph;

    // ---- v-pass: vt[row] = lnu - LSE_i(GpT[row,i] + ut[i]) ----
    stage_pot(ut, s_pot, t);
    __syncthreads();
    {
      float nv = lnu_r - lse_row(grow_v, s_pot, lane);
      if (lane == 0)
        __hip_atomic_store(&vt[row], nv, __ATOMIC_RELAXED,
                           __HIP_MEMORY_SCOPE_AGENT);
    }
    gridbar(grp, gbar, g, ph); ++ph;
  }
}

// ---------------------------------------------------------------------------
// RT[d,i] = sum_j TF[d,j] * exp( GpT[j*S+i] + ut[i] + vt[j] )
// ---------------------------------------------------------------------------
__global__ __launch_bounds__(256) void rt_gemm_k(const float* __restrict__ TF,
                                                 const float* __restrict__ GpT,
                                                 const float* __restrict__ ut,
                                                 const float* __restrict__ vt,
                                                 float* __restrict__ RT) {
  __shared__ float As[16][128];
  __shared__ float Bs[16][128];
  int t = threadIdx.x;
  int d0 = blockIdx.y * 128, i0 = blockIdx.x * 128;
  int tx = t & 15, ty = t >> 4;
  float acc[8][8];
#pragma unroll
  for (int r = 0; r < 8; ++r)
#pragma unroll
    for (int c = 0; c < 8; ++c) acc[r][c] = 0.f;

  int akk = (t * 4) & 15, add0 = t >> 2;
  int eb = t * 4;
  int bkk0 = eb >> 7, bii = eb & 127, bkk1 = bkk0 + 8;
  float4 u4 = *(const float4*)&ut[i0 + bii];

  for (int k0 = 0; k0 < S; k0 += 16) {
    float4 av0 = *(const float4*)&TF[(d0 + add0) * S + k0 + akk];
    float4 av1 = *(const float4*)&TF[(d0 + add0 + 64) * S + k0 + akk];
    float4 g0 = *(const float4*)&GpT[(k0 + bkk0) * S + i0 + bii];
    float4 g1 = *(const float4*)&GpT[(k0 + bkk1) * S + i0 + bii];
    float v0 = vt[k0 + bkk0], v1 = vt[k0 + bkk1];
    __syncthreads();
    As[akk + 0][add0] = av0.x; As[akk + 1][add0] = av0.y;
    As[akk + 2][add0] = av0.z; As[akk + 3][add0] = av0.w;
    As[akk + 0][add0 + 64] = av1.x; As[akk + 1][add0 + 64] = av1.y;
    As[akk + 2][add0 + 64] = av1.z; As[akk + 3][add0 + 64] = av1.w;
    float4 p0 = make_float4(__expf(g0.x + u4.x + v0), __expf(g0.y + u4.y + v0),
                            __expf(g0.z + u4.z + v0), __expf(g0.w + u4.w + v0));
    float4 p1 = make_float4(__expf(g1.x + u4.x + v1), __expf(g1.y + u4.y + v1),
                            __expf(g1.z + u4.z + v1), __expf(g1.w + u4.w + v1));
    *(float4*)&Bs[bkk0][bii] = p0;
    *(float4*)&Bs[bkk1][bii] = p1;
    __syncthreads();
#pragma unroll
    for (int kk = 0; kk < 16; ++kk) {
      float a[8], b[8];
      *(float4*)&a[0] = *(const float4*)&As[kk][ty * 8];
      *(float4*)&a[4] = *(const float4*)&As[kk][ty * 8 + 4];
      *(float4*)&b[0] = *(const float4*)&Bs[kk][tx * 4];
      *(float4*)&b[4] = *(const float4*)&Bs[kk][64 + tx * 4];
#pragma unroll
      for (int r = 0; r < 8; ++r)
#pragma unroll
        for (int c = 0; c < 8; ++c) acc[r][c] = fmaf(a[r], b[c], acc[r][c]);
    }
  }
#pragma unroll
  for (int r = 0; r < 8; ++r) {
    int d = d0 + ty * 8 + r;
    *(float4*)&RT[d * S + i0 + tx * 4] = *(float4*)&acc[r][0];
    *(float4*)&RT[d * S + i0 + 64 + tx * 4] = *(float4*)&acc[r][4];
  }
}

// dist2[i] += sum_{d in chunk} (qa[i]*QF[d,i] - RT[d,i])^2
__global__ __launch_bounds__(256) void dist2_partial_k(const float* __restrict__ QF,
                                                       const float* __restrict__ RT,
                                                       const float* __restrict__ qa,
                                                       float* __restrict__ dist2) {
  int ib = blockIdx.x & 7, dc = blockIdx.x >> 3;
  int i = ib * 256 + threadIdx.x;
  float qai = qa[i];
  float acc = 0.f;
  int d0 = dc * 256;
  for (int d = d0; d < d0 + 256; ++d) {
    float q = QF[d * S + i];
    float r = RT[d * S + i];
    float x = fmaf(qai, q, -r);
    acc = fmaf(x, x, acc);
  }
  atomicAdd(&dist2[i], acc);
}

__global__ __launch_bounds__(256) void loss_final_k(const float* __restrict__ dist2,
                                                    const float* __restrict__ label,
                                                    float* __restrict__ out) {
  int t = threadIdx.x;
  float acc = 0.f;
#pragma unroll
  for (int k = 0; k < 8; ++k) {
    int i = t + k * 256;
    float d2 = dist2[i];
    float dist = sqrtf(d2);
    float lab = label[i];
    float neg = fmaxf(MARGIN - dist, 0.f);
    acc += 0.5f * lab * d2 + 0.5f * (1.f - lab) * neg * neg;
  }
#pragma unroll
  for (int off = 32; off; off >>= 1) acc += __shfl_xor(acc, off);
  __shared__ float wsum[4];
  int wave = t >> 6, lane = t & 63;
  if (lane == 0) wsum[wave] = acc;
  __syncthreads();
  if (t == 0) out[0] = wsum[0] + wsum[1] + wsum[2] + wsum[3];
}

// ---------------------------------------------------------------------------
extern "C" void kernel_launch(void* const* d_in, const int* in_sizes, int n_in,
                              void* d_out, int out_size, void* d_ws, size_t ws_size,
                              hipStream_t stream) {
  const float* QF  = (const float*)d_in[0];  // [D, m] d-major
  const float* qa  = (const float*)d_in[1];  // [m]
  const float* TF  = (const float*)d_in[2];  // [D, n] d-major
  const float* ta  = (const float*)d_in[3];  // [n]
  const float* lab = (const float*)d_in[4];  // [m]
  float* out = (float*)d_out;

  float* ws = (float*)d_ws;
  float* Gp    = ws;                  // S*S : G' = -2 X^T Y  (reused as RT later)
  float* GpT   = Gp + S * S;          // S*S : G'^T
  float* ut    = GpT + S * S;         // S
  float* vt    = ut + S;              // S
  float* lmu   = vt + S;              // S
  float* lnu   = lmu + S;             // S
  float* dist2 = lnu + S;             // S
  unsigned* grp  = (unsigned*)(dist2 + S);  // 512 : group counters (stride 32)
  unsigned* gbar = grp + 512;               // 1   : global phase counter
  // total: 2*S*S + 5*S floats + 513 u32 ~= 33.6 MB

  init_marg_k<<<8, 256, 0, stream>>>(qa, ta, lmu, lnu, vt, dist2, grp, gbar);
  colsumsq_k<<<64, 256, 0, stream>>>(TF, vt);  // vt = y2 (== v0 + y2)
  gemm_tn_k<<<dim3(16, 16), 256, 0, stream>>>(QF, TF, Gp, -2.0f);
  transpose_k<<<dim3(32, 32), 256, 0, stream>>>(Gp, GpT);

  // whole Sinkhorn loop in one persistent cooperative kernel (static 136KB LDS)
  {
    const float* cGp = Gp; const float* cGpT = GpT;
    const float* clmu = lmu; const float* clnu = lnu;
    float* cut = ut; float* cvt = vt;
    unsigned* cgrp = grp; unsigned* cgbar = gbar;
    void* kargs[] = {&cGp, &cGpT, &clmu, &clnu, &cut, &cvt, &cgrp, &cgbar};
    hipLaunchCooperativeKernel((const void*)sinkhorn_k, dim3(NBLK), dim3(TPB),
                               kargs, 0, stream);
  }

  // RT = P @ tf computed transposed: RT[d,i]; aliases Gp (G' dead after loop)
  rt_gemm_k<<<dim3(16, 16), 256, 0, stream>>>(TF, GpT, ut, vt, Gp);
  dist2_partial_k<<<64, 256, 0, stream>>>(QF, Gp, qa, dist2);
  loss_final_k<<<1, 256, 0, stream>>>(dist2, lab, out);
}